// Round 1
// baseline (753.585 us; speedup 1.0000x reference)
//
#include <hip/hip_runtime.h>
#include <hip/hip_bf16.h>

// Problem constants
#define NNEUR 8192
#define NCONV 64
#define LYC   36
#define LXC   36
#define BATCH 256
#define KRAW  1296   // 36*36
#define KPAD  1312   // 41*32, zero-padded K for 16x16x32 MFMA
#define MROWS 16384  // BATCH*NCONV

typedef __attribute__((ext_vector_type(8))) _Float16 half8;
typedef __attribute__((ext_vector_type(4))) float f32x4;

__device__ __forceinline__ void async_copy16(const void* g, void* l) {
  __builtin_amdgcn_global_load_lds(
      (const __attribute__((address_space(1))) void*)g,
      (__attribute__((address_space(3))) void*)l, 16, 0, 0);
}

// Cast conv [16384][1296] fp32 -> f16 padded to [16384][1312]
__global__ void conv_cast_kernel(const float* __restrict__ conv,
                                 _Float16* __restrict__ A) {
  const int row = blockIdx.x;
  const float* src = conv + (size_t)row * KRAW;
  _Float16* dst = A + (size_t)row * KPAD;
  for (int k = threadIdx.x; k < KPAD; k += 256)
    dst[k] = (_Float16)(k < KRAW ? src[k] : 0.f);
}

// Wyx[n][y*36+x] = Wy[n,y]*Wx[n,x]*256 (scaled to avoid f16 subnormals), padded
__global__ void build_wyx_kernel(const float* __restrict__ Wy,
                                 const float* __restrict__ Wx,
                                 _Float16* __restrict__ B) {
  const int n = blockIdx.x;
  const float* wy = Wy + n * LYC;
  const float* wx = Wx + n * LXC;
  _Float16* dst = B + (size_t)n * KPAD;
  for (int k = threadIdx.x; k < KPAD; k += 256) {
    float v = 0.f;
    if (k < KRAW) {
      int y = k / LXC;
      int x = k - y * LXC;
      v = wy[y] * wx[x] * 256.f;
    }
    dst[k] = (_Float16)v;
  }
}

// Fused GEMM: s[ic,n] = sum_k A[ic,k]*B[n,k]; epilogue reduces over c with Wc,
// adds bias, applies ELU, writes out[i,n]. 128x128 tile per block, 4 waves.
__global__ __launch_bounds__(256) void gemm_fused_kernel(
    const _Float16* __restrict__ A, const _Float16* __restrict__ B,
    const float* __restrict__ Wc, const float* __restrict__ bias,
    float* __restrict__ out) {
  __shared__ _Float16 As[128 * 32];
  __shared__ _Float16 Bs[128 * 32];

  const int tileN = blockIdx.x * 128;
  const int tileM = blockIdx.y * 128;
  const int t = threadIdx.x;
  const int lane = t & 63;
  const int wave = t >> 6;
  const int wm = wave >> 1, wn = wave & 1;  // 2x2 waves, each 64x64
  const int quad = lane >> 4, col = lane & 15;

  f32x4 acc[4][4] = {};

  // Staging: 512 16B-chunks per tile operand; thread t does chunks t and t+256.
  // Chunk c -> LDS bytes [c*16, c*16+16) = row c>>2, k-offset (c&3)*8 elements.
  const int rowS = t >> 2;
  const int kS = (t & 3) * 8;
  const _Float16* gA0 = A + (size_t)(tileM + rowS) * KPAD + kS;
  const _Float16* gA1 = gA0 + (size_t)64 * KPAD;
  const _Float16* gB0 = B + (size_t)(tileN + rowS) * KPAD + kS;
  const _Float16* gB1 = gB0 + (size_t)64 * KPAD;
  _Float16* lA0 = As + t * 8;
  _Float16* lA1 = As + (t + 256) * 8;
  _Float16* lB0 = Bs + t * 8;
  _Float16* lB1 = Bs + (t + 256) * 8;

  for (int kk = 0; kk < KPAD; kk += 32) {
    async_copy16(gA0 + kk, lA0);
    async_copy16(gA1 + kk, lA1);
    async_copy16(gB0 + kk, lB0);
    async_copy16(gB1 + kk, lB1);
    __syncthreads();  // compiler emits vmcnt(0) drain before barrier

    half8 af[4], bfr[4];
#pragma unroll
    for (int ms = 0; ms < 4; ms++)
      af[ms] = *(const half8*)(As + (wm * 64 + ms * 16 + col) * 32 + quad * 8);
#pragma unroll
    for (int ns = 0; ns < 4; ns++)
      bfr[ns] = *(const half8*)(Bs + (wn * 64 + ns * 16 + col) * 32 + quad * 8);
#pragma unroll
    for (int ms = 0; ms < 4; ms++)
#pragma unroll
      for (int ns = 0; ns < 4; ns++)
        acc[ms][ns] = __builtin_amdgcn_mfma_f32_16x16x32_f16(
            af[ms], bfr[ns], acc[ms][ns], 0, 0, 0);
    __syncthreads();
  }

  // Epilogue: wave (wm,wn) holds s rows (64 channels of image i_idx) x 64 n.
  // C/D layout: col = lane&15, row = quad*4 + reg  (rows here are channels).
  const int i_idx = (tileM >> 6) + wm;  // batch index
  float red[4];
#pragma unroll
  for (int ns = 0; ns < 4; ns++) {
    const int n_g = tileN + wn * 64 + ns * 16 + col;
    const float* wc = Wc + (size_t)n_g * NCONV;
    float p = 0.f;
#pragma unroll
    for (int ms = 0; ms < 4; ms++) {
      const f32x4 w = *(const f32x4*)(wc + ms * 16 + quad * 4);
      p += acc[ms][ns][0] * w[0] + acc[ms][ns][1] * w[1] +
           acc[ms][ns][2] * w[2] + acc[ms][ns][3] * w[3];
    }
    p += __shfl_xor(p, 16);
    p += __shfl_xor(p, 32);
    red[ns] = p;
  }
  // quad q stores ns=q; value uniform across quads after butterfly
  float v = quad == 0 ? red[0] : quad == 1 ? red[1] : quad == 2 ? red[2] : red[3];
  const int n_out = tileN + wn * 64 + quad * 16 + col;
  v = v * 0.00390625f + bias[n_out];  // undo Wyx x256 scaling, add bias
  v = v > 0.f ? v : (__expf(v) - 1.f);
  out[(size_t)i_idx * NNEUR + n_out] = v;
}

extern "C" void kernel_launch(void* const* d_in, const int* in_sizes, int n_in,
                              void* d_out, int out_size, void* d_ws,
                              size_t ws_size, hipStream_t stream) {
  const float* conv = (const float*)d_in[0];
  const float* Wc = (const float*)d_in[1];
  const float* Wy = (const float*)d_in[2];
  const float* Wx = (const float*)d_in[3];
  const float* bias = (const float*)d_in[4];
  float* out = (float*)d_out;

  _Float16* Abuf = (_Float16*)d_ws;                               // 16384*1312*2 B
  _Float16* Bbuf = (_Float16*)((char*)d_ws + (size_t)MROWS * KPAD * 2);  // 8192*1312*2 B

  conv_cast_kernel<<<MROWS, 256, 0, stream>>>(conv, Abuf);
  build_wyx_kernel<<<NNEUR, 256, 0, stream>>>(Wy, Wx, Bbuf);

  dim3 grid(NNEUR / 128, MROWS / 128);  // (64, 128)
  gemm_fused_kernel<<<grid, 256, 0, stream>>>(Abuf, Bbuf, Wc, bias, out);
}

// Round 2
// 531.870 us; speedup vs baseline: 1.4169x; 1.4169x over previous
//
#include <hip/hip_runtime.h>
#include <hip/hip_bf16.h>

// Problem constants
#define NNEUR 8192
#define NCONV 64
#define LYC   36
#define LXC   36
#define BATCH 256
#define KRAW  1296   // 36*36
#define KPAD  1344   // 21*64, zero-padded K for BK=64 loop
#define ASLOT 168    // KPAD/8 half8-slots per row
#define MROWS 16384  // BATCH*NCONV

typedef __attribute__((ext_vector_type(8))) _Float16 half8;
typedef __attribute__((ext_vector_type(4))) float f32x4;

__device__ __forceinline__ void async_copy16(const void* g, void* l) {
  __builtin_amdgcn_global_load_lds(
      (const __attribute__((address_space(1))) void*)g,
      (__attribute__((address_space(3))) void*)l, 16, 0, 0);
}

// Cast conv [16384][1296] fp32 -> f16 padded to [16384][1344], half8 stores.
__global__ __launch_bounds__(256) void conv_cast_kernel(
    const float* __restrict__ conv, _Float16* __restrict__ A) {
  const int slot = blockIdx.x * 256 + threadIdx.x;
  if (slot >= MROWS * ASLOT) return;
  const int row = slot / ASLOT;
  const int j = slot - row * ASLOT;
  half8 h;
  if (j < 162) {  // 162*8 = 1296 exactly
    const float* s = conv + (size_t)row * KRAW + j * 8;
#pragma unroll
    for (int e = 0; e < 8; e++) h[e] = (_Float16)s[e];
  } else {
#pragma unroll
    for (int e = 0; e < 8; e++) h[e] = (_Float16)0.f;
  }
  *(half8*)(A + (size_t)row * KPAD + j * 8) = h;
}

// Wyx[n][y*36+x] = Wy[n,y]*Wx[n,x]*256 (scaled vs f16 subnormals), padded.
__global__ __launch_bounds__(256) void build_wyx_kernel(
    const float* __restrict__ Wy, const float* __restrict__ Wx,
    _Float16* __restrict__ B) {
  const int slot = blockIdx.x * 256 + threadIdx.x;
  if (slot >= NNEUR * ASLOT) return;
  const int n = slot / ASLOT;
  const int j = slot - n * ASLOT;
  half8 h;
#pragma unroll
  for (int e = 0; e < 8; e++) {
    const int k = j * 8 + e;
    float v = 0.f;
    if (k < KRAW) {
      const int y = k / LXC;  // compiler magic-muls constant div
      const int x = k - y * LXC;
      v = Wy[n * LYC + y] * Wx[n * LXC + x] * 256.f;
    }
    h[e] = (_Float16)v;
  }
  *(half8*)(B + (size_t)n * KPAD + j * 8) = h;
}

// Fused GEMM: s[ic,n] = sum_k A[ic,k]*B[n,k]; epilogue contracts c with Wc,
// adds bias, ELU. 128x128 tile, BK=64, XOR-swizzled LDS (conflict-free), XCD
// block swizzle. LDS row = 64 halfs = 128 B = 32 banks; chunk c of row r is
// stored at slot (c+r)&7 — realized by permuting the SOURCE chunk each thread
// stages (global_load_lds dst must stay lane-contiguous).
__global__ __launch_bounds__(256, 3) void gemm_fused_kernel(
    const _Float16* __restrict__ A, const _Float16* __restrict__ B,
    const float* __restrict__ Wc, const float* __restrict__ bias,
    float* __restrict__ out) {
  __shared__ _Float16 As[128 * 64];
  __shared__ _Float16 Bs[128 * 64];

  // XCD-aware swizzle: blocks dispatched round-robin over 8 XCDs; give each
  // XCD a contiguous n-range so its B-tile (336 KB) stays L2-resident.
  const int flat = blockIdx.x;         // 0..8191
  const int xcd = flat & 7;
  const int local = flat >> 3;         // 0..1023
  const int tileN = (xcd * 8 + (local >> 7)) * 128;  // 64 n-tiles
  const int tileM = (local & 127) * 128;             // 128 m-tiles

  const int t = threadIdx.x;
  const int lane = t & 63;
  const int wave = t >> 6;
  const int wm = wave >> 1, wn = wave & 1;  // 2x2 waves, each 64x64
  const int quad = lane >> 4, col = lane & 15;

  f32x4 acc[4][4] = {};

  // Staging: per operand per iter, 1024 16B-chunks (128 rows x 8 chunks).
  // Thread t handles chunks p = t + 256*i -> row (t>>3)+32*i, slot t&7.
  // Swizzle: actual source chunk c = (slot - row)&7 (invariant across i).
  const int rbase = t >> 3;                       // 0..31
  const int cchunk = ((t & 7) - rbase) & 7;       // source chunk index
  const int koff = cchunk * 8;                    // halfs
  const _Float16* gA = A + (size_t)(tileM + rbase) * KPAD + koff;
  const _Float16* gB = B + (size_t)(tileN + rbase) * KPAD + koff;
  _Float16* lA = As + t * 8;  // byte t*16, lane-contiguous per issue
  _Float16* lB = Bs + t * 8;

  for (int kk = 0; kk < KPAD; kk += 64) {
#pragma unroll
    for (int i = 0; i < 4; i++) {
      async_copy16(gA + kk + (size_t)(32 * i) * KPAD, lA + i * 2048);
      async_copy16(gB + kk + (size_t)(32 * i) * KPAD, lB + i * 2048);
    }
    __syncthreads();

#pragma unroll
    for (int s = 0; s < 2; s++) {  // two K=32 substeps
      half8 af[4], bfr[4];
#pragma unroll
      for (int ms = 0; ms < 4; ms++) {
        const int r = wm * 64 + ms * 16 + col;
        af[ms] = *(const half8*)(As + r * 64 + (((s << 2) + quad + r) & 7) * 8);
      }
#pragma unroll
      for (int ns = 0; ns < 4; ns++) {
        const int r = wn * 64 + ns * 16 + col;
        bfr[ns] = *(const half8*)(Bs + r * 64 + (((s << 2) + quad + r) & 7) * 8);
      }
#pragma unroll
      for (int ms = 0; ms < 4; ms++)
#pragma unroll
        for (int ns = 0; ns < 4; ns++)
          acc[ms][ns] = __builtin_amdgcn_mfma_f32_16x16x32_f16(
              af[ms], bfr[ns], acc[ms][ns], 0, 0, 0);
    }
    __syncthreads();
  }

  // Epilogue: wave (wm,wn) holds s rows (64 channels of image i_idx) x 64 n.
  // C/D layout: col = lane&15, row = quad*4 + reg (rows here are channels).
  const int i_idx = (tileM >> 6) + wm;  // batch index
  float red[4];
#pragma unroll
  for (int ns = 0; ns < 4; ns++) {
    const int n_g = tileN + wn * 64 + ns * 16 + col;
    const float* wc = Wc + (size_t)n_g * NCONV;
    float p = 0.f;
#pragma unroll
    for (int ms = 0; ms < 4; ms++) {
      const f32x4 w = *(const f32x4*)(wc + ms * 16 + quad * 4);
      p += acc[ms][ns][0] * w[0] + acc[ms][ns][1] * w[1] +
           acc[ms][ns][2] * w[2] + acc[ms][ns][3] * w[3];
    }
    p += __shfl_xor(p, 16);
    p += __shfl_xor(p, 32);
    red[ns] = p;
  }
  float v = quad == 0 ? red[0] : quad == 1 ? red[1] : quad == 2 ? red[2] : red[3];
  const int n_out = tileN + wn * 64 + quad * 16 + col;
  v = v * 0.00390625f + bias[n_out];  // undo Wyx x256 scaling, add bias
  v = v > 0.f ? v : (__expf(v) - 1.f);
  out[(size_t)i_idx * NNEUR + n_out] = v;
}

extern "C" void kernel_launch(void* const* d_in, const int* in_sizes, int n_in,
                              void* d_out, int out_size, void* d_ws,
                              size_t ws_size, hipStream_t stream) {
  const float* conv = (const float*)d_in[0];
  const float* Wc = (const float*)d_in[1];
  const float* Wy = (const float*)d_in[2];
  const float* Wx = (const float*)d_in[3];
  const float* bias = (const float*)d_in[4];
  float* out = (float*)d_out;

  _Float16* Abuf = (_Float16*)d_ws;                                      // 44.0 MB
  _Float16* Bbuf = (_Float16*)((char*)d_ws + (size_t)MROWS * KPAD * 2);  // 22.0 MB

  conv_cast_kernel<<<(MROWS * ASLOT + 255) / 256, 256, 0, stream>>>(conv, Abuf);
  build_wyx_kernel<<<(NNEUR * ASLOT + 255) / 256, 256, 0, stream>>>(Wy, Wx, Bbuf);

  gemm_fused_kernel<<<8192, 256, 0, stream>>>(Abuf, Bbuf, Wc, bias, out);
}

// Round 3
// 481.096 us; speedup vs baseline: 1.5664x; 1.1055x over previous
//
#include <hip/hip_runtime.h>
#include <hip/hip_bf16.h>

// Problem constants
#define NNEUR 8192
#define NCONV 64
#define LYC   36
#define LXC   36
#define BATCH 256
#define KRAW  1296   // 36*36
#define KPAD  1344   // 21*64
#define KITER 21     // KPAD/64
#define MROWS 16384  // BATCH*NCONV
#define BM 256
#define BN 128
#define BK 64
// Staged-chunk geometry: one chunk = 16 B = 8 halfs.
#define ACH_PER_IT 2048   // BM*BK/8
#define BCH_PER_IT 1024   // BN*BK/8
#define A_TILE_H   (KITER * ACH_PER_IT * 8)  // halfs per m-tile = 344064
#define B_TILE_H   (KITER * BCH_PER_IT * 8)  // halfs per n-tile = 172032

typedef __attribute__((ext_vector_type(8))) _Float16 half8;
typedef __attribute__((ext_vector_type(4))) float f32x4;
typedef __attribute__((ext_vector_type(16))) float f32x16;

__device__ __forceinline__ void async_copy16(const void* g, void* l) {
  __builtin_amdgcn_global_load_lds(
      (const __attribute__((address_space(1))) void*)g,
      (__attribute__((address_space(3))) void*)l, 16, 0, 0);
}

// Prep: emit A (conv->f16) and B (Wy*Wx*256->f16) directly in the GEMM's
// staged LDS-image order, bank-XOR swizzle baked in: within a BK=64 row
// (8 chunks of 16B), source chunk c lives at slot (c+row)&7. Staged layout
// per tile/iter is exactly the order 256 threads issue global_load_lds.
// grid: x = 0..167 -> A (it = x>>3, i = x&7); x = 168..251 -> B (x'=x-168,
// it = x'>>2, i = x'&3); y = tile index (64 m-tiles / 64 n-tiles).
__global__ __launch_bounds__(256) void prep_kernel(
    const float* __restrict__ conv, const float* __restrict__ Wy,
    const float* __restrict__ Wx, _Float16* __restrict__ A,
    _Float16* __restrict__ B) {
  const int t = threadIdx.x;
  const int bx = blockIdx.x;
  const int tile = blockIdx.y;
  const int slot = t & 7;
  half8 h;
  if (bx < 168) {  // A part
    const int it = bx >> 3, i = bx & 7;
    const int r = (t >> 3) + 32 * i;                 // row in tile, 0..255
    const int c = (slot - r) & 7;                    // source chunk
    const int k0 = it * 64 + c * 8;
    const int grow = tile * BM + r;
    if (k0 < KRAW) {
      const float* s = conv + (size_t)grow * KRAW + k0;
#pragma unroll
      for (int e = 0; e < 8; e++) h[e] = (_Float16)s[e];
    } else {
#pragma unroll
      for (int e = 0; e < 8; e++) h[e] = (_Float16)0.f;
    }
    *(half8*)(A + (size_t)tile * A_TILE_H + ((size_t)bx * 256 + t) * 8) = h;
  } else {  // B part
    const int bx4 = bx - 168;
    const int it = bx4 >> 2, i = bx4 & 3;
    const int r = (t >> 3) + 32 * i;                 // row in tile, 0..127
    const int c = (slot - r) & 7;
    const int k0 = it * 64 + c * 8;
    const int n = tile * BN + r;
#pragma unroll
    for (int e = 0; e < 8; e++) {
      const int k = k0 + e;
      float v = 0.f;
      if (k < KRAW) {
        const int y = k / LXC;
        const int x = k - y * LXC;
        v = Wy[n * LYC + y] * Wx[n * LXC + x] * 256.f;
      }
      h[e] = (_Float16)v;
    }
    *(half8*)(B + (size_t)tile * B_TILE_H + ((size_t)bx4 * 256 + t) * 8) = h;
  }
}

// Fused GEMM: block tile 256(M)x128(N), BK=64, 4 waves each 128x64 using
// 32x32x16 f16 MFMA (acc 8 x f32x16 = 128 AGPR). Epilogue contracts the 64
// channels with Wc, adds bias, ELU. LDS 48 KB single-buffered.
__global__ __launch_bounds__(256, 3) void gemm_fused_kernel(
    const _Float16* __restrict__ A, const _Float16* __restrict__ B,
    const float* __restrict__ Wc, const float* __restrict__ bias,
    float* __restrict__ out) {
  __shared__ _Float16 As[BM * BK];  // 32 KB
  __shared__ _Float16 Bs[BN * BK];  // 16 KB

  // XCD swizzle: xcd = bid&7; within an XCD, n varies fastest so the 8
  // blocks sharing one A-tile are consecutive; B panel (8 n-tiles, 2.75 MB)
  // stays L2-resident per XCD.
  const int bid = blockIdx.x;      // 0..4095
  const int l = bid >> 3;          // 0..511
  const int ntile = (bid & 7) * 8 + (l & 7);  // 0..63
  const int mtile = l >> 3;                   // 0..63
  const int tileN = ntile * BN;
  const int tileM = mtile * BM;

  const int t = threadIdx.x;
  const int lane = t & 63;
  const int wave = t >> 6;
  const int wm = wave >> 1, wn = wave & 1;  // 2x2 waves; wave tile 128x64
  const int r32 = lane & 31, hh = lane >> 5;

  f32x16 acc[4][2] = {};  // [mb][nb], mb: 4x32 rows, nb: 2x32 cols

  const _Float16* pA = A + (size_t)mtile * A_TILE_H;
  const _Float16* pB = B + (size_t)ntile * B_TILE_H;
  _Float16* lA = As + t * 8;
  _Float16* lB = Bs + t * 8;

  for (int it = 0; it < KITER; it++) {
    const _Float16* sA = pA + (size_t)it * (ACH_PER_IT * 8) + t * 8;
    const _Float16* sB = pB + (size_t)it * (BCH_PER_IT * 8) + t * 8;
#pragma unroll
    for (int i = 0; i < 8; i++) async_copy16(sA + i * 2048, lA + i * 2048);
#pragma unroll
    for (int i = 0; i < 4; i++) async_copy16(sB + i * 2048, lB + i * 2048);
    __syncthreads();

#pragma unroll
    for (int ks = 0; ks < 4; ks++) {
      const int cc = 2 * ks + hh;  // source chunk for this k-substep
      half8 bf[2];
#pragma unroll
      for (int nb = 0; nb < 2; nb++) {
        const int r = wn * 64 + nb * 32 + r32;
        bf[nb] = *(const half8*)(Bs + r * 64 + ((cc + r) & 7) * 8);
      }
#pragma unroll
      for (int mb = 0; mb < 4; mb++) {
        const int r = wm * 128 + mb * 32 + r32;
        const half8 af = *(const half8*)(As + r * 64 + ((cc + r) & 7) * 8);
#pragma unroll
        for (int nb = 0; nb < 2; nb++)
          acc[mb][nb] = __builtin_amdgcn_mfma_f32_32x32x16_f16(
              af, bf[nb], acc[mb][nb], 0, 0, 0);
      }
    }
    __syncthreads();
  }

  // Epilogue. C/D layout (32x32): col = lane&31, row = (reg&3)+8*(reg>>2)+4*hh.
  // Wave rows = 128 = 2 images x 64 channels; mb pairs (0,1)->img0, (2,3)->img1;
  // channel = (mb&1)*32 + row.
  const int ibase = mtile * 4 + wm * 2;
  float v[2][2];  // [img][nb]
#pragma unroll
  for (int nb = 0; nb < 2; nb++) {
    const int n_g = tileN + wn * 64 + nb * 32 + r32;
    const float* wc = Wc + (size_t)n_g * NCONV;
    f32x4 w[2][4];
#pragma unroll
    for (int hf = 0; hf < 2; hf++)
#pragma unroll
      for (int g = 0; g < 4; g++)
        w[hf][g] = *(const f32x4*)(wc + hf * 32 + hh * 4 + g * 8);
#pragma unroll
    for (int img = 0; img < 2; img++) {
      float p = 0.f;
#pragma unroll
      for (int hf = 0; hf < 2; hf++)
#pragma unroll
        for (int g = 0; g < 4; g++)
#pragma unroll
          for (int q = 0; q < 4; q++)
            p += acc[img * 2 + hf][nb][g * 4 + q] * w[hf][g][q];
      p += __shfl_xor(p, 32);
      v[img][nb] = p;
    }
  }
  // Each lane writes image hh (its half), both nb; values identical per half.
  const int img = ibase + hh;
#pragma unroll
  for (int nb = 0; nb < 2; nb++) {
    const int n_out = tileN + wn * 64 + nb * 32 + r32;
    float z = v[hh][nb] * 0.00390625f + bias[n_out];  // undo x256 scaling
    z = z > 0.f ? z : (__expf(z) - 1.f);
    out[(size_t)img * NNEUR + n_out] = z;
  }
}

extern "C" void kernel_launch(void* const* d_in, const int* in_sizes, int n_in,
                              void* d_out, int out_size, void* d_ws,
                              size_t ws_size, hipStream_t stream) {
  const float* conv = (const float*)d_in[0];
  const float* Wc = (const float*)d_in[1];
  const float* Wy = (const float*)d_in[2];
  const float* Wx = (const float*)d_in[3];
  const float* bias = (const float*)d_in[4];
  float* out = (float*)d_out;

  _Float16* Abuf = (_Float16*)d_ws;                                      // 44.0 MB
  _Float16* Bbuf = (_Float16*)((char*)d_ws + (size_t)MROWS * KPAD * 2);  // 22.0 MB

  prep_kernel<<<dim3(252, 64), 256, 0, stream>>>(conv, Wy, Wx, Abuf, Bbuf);
  gemm_fused_kernel<<<4096, 256, 0, stream>>>(Abuf, Bbuf, Wc, bias, out);
}